// Round 2
// baseline (4009.076 us; speedup 1.0000x reference)
//
#include <hip/hip_runtime.h>
#include <hip/hip_bf16.h>
#include <math.h>

// Problem constants
#define BN 4
#define CC 256
#define HH_ 128
#define WW_ 128
#define HWP (HH_*WW_)           // 16384 pixels
#define TOK (64*HWP)            // 1,048,576 elems per (scale,batch) token matrix

// Workspace layout (bytes). Total = 167,839,744 B (~160.1 MiB).
//  qt : bf16 [4 scale][4 b][n][D]   33,554,432 B
//  kt : bf16                        33,554,432 B
//  vt : bf16                        33,554,432 B
//  ao : bf16 [b][256][128][128]     33,554,432 B (attention out, conv input)
//  Sbf: bf16 score buffer (reused)  33,554,432 B (scale0 per-batch 4096^2)
//  stats: 512 fp32                  2,048 B
//  S3 : fp32 [4][64][64]            65,536 B (scale-3 K-split atomic acc)

__device__ __forceinline__ float bf2f(unsigned short u) {
    return __uint_as_float(((unsigned)u) << 16);
}
__device__ __forceinline__ unsigned short f2bf(float f) {
    unsigned u = __float_as_uint(f);
    u += 0x7FFF + ((u >> 16) & 1);
    return (unsigned short)(u >> 16);
}
__device__ __forceinline__ void load4f(const unsigned short* p, float o[4]) {
    ushort4 v = *(const ushort4*)p;
    o[0] = bf2f(v.x); o[1] = bf2f(v.y); o[2] = bf2f(v.z); o[3] = bf2f(v.w);
}
__device__ __forceinline__ void load4f(const float* p, float o[4]) {
    float4 v = *(const float4*)p;
    o[0] = v.x; o[1] = v.y; o[2] = v.z; o[3] = v.w;
}
__device__ __forceinline__ float ld1(const unsigned short* p) { return bf2f(*p); }
__device__ __forceinline__ float ld1(const float* p) { return *p; }
__device__ __forceinline__ void st1(unsigned short* p, float v) { *p = f2bf(v); }
__device__ __forceinline__ void st1(float* p, float v) { *p = v; }

// ---------------------------------------------------------------------------
__global__ __launch_bounds__(256) void zero_kernel(float* __restrict__ p)
{
    p[blockIdx.x * 256 + threadIdx.x] = 0.f;
}

// ---------------------------------------------------------------------------
// 1x1 conv (channel GEMM) for q/k/v, scatter-stored bf16 into token layout.
// grid: (HWP/64, CC/64, 12)  z = which*4 + b, which: 0=q(x),1=k(y),2=v(y)
__global__ __launch_bounds__(256) void proj_kernel(
    const float* __restrict__ xin, const float* __restrict__ yin,
    const float* __restrict__ Wq, const float* __restrict__ bq,
    const float* __restrict__ Wk, const float* __restrict__ bk,
    const float* __restrict__ Wv, const float* __restrict__ bv,
    unsigned short* __restrict__ qt, unsigned short* __restrict__ kt,
    unsigned short* __restrict__ vt)
{
    int z = blockIdx.z;
    int b = z & 3, which = z >> 2;
    const float* in   = (which == 0) ? xin : yin;
    const float* Wm   = (which == 0) ? Wq : (which == 1 ? Wk : Wv);
    const float* bias = (which == 0) ? bq : (which == 1 ? bk : bv);
    unsigned short* outp = (which == 0) ? qt : (which == 1 ? kt : vt);
    in += (size_t)b * CC * HWP;

    int p0 = blockIdx.x * 64;
    int o0 = blockIdx.y * 64;

    __shared__ float Ws[16][64];   // [k][o]
    __shared__ float Xs[16][64];   // [k][p]

    int t = threadIdx.x;
    int tx = t & 15, ty = t >> 4;
    int r = t >> 2, q = t & 3;
    int xr = t >> 4, xq = t & 15;

    float acc[4][4] = {};
    for (int c0 = 0; c0 < CC; c0 += 16) {
        float4 wv = *(const float4*)&Wm[(size_t)(o0 + r) * CC + c0 + q * 4];
        float4 xv = *(const float4*)&in[(size_t)(c0 + xr) * HWP + p0 + xq * 4];
        __syncthreads();
        Ws[q*4+0][r] = wv.x; Ws[q*4+1][r] = wv.y; Ws[q*4+2][r] = wv.z; Ws[q*4+3][r] = wv.w;
        *(float4*)&Xs[xr][xq * 4] = xv;
        __syncthreads();
        #pragma unroll
        for (int k = 0; k < 16; k++) {
            float4 af = *(const float4*)&Ws[k][ty*4];
            float4 bf = *(const float4*)&Xs[k][tx*4];
            float ar[4] = {af.x, af.y, af.z, af.w};
            float br[4] = {bf.x, bf.y, bf.z, bf.w};
            #pragma unroll
            for (int ii = 0; ii < 4; ii++)
                #pragma unroll
                for (int jj = 0; jj < 4; jj++)
                    acc[ii][jj] = fmaf(ar[ii], br[jj], acc[ii][jj]);
        }
    }

    // scatter to token layout (bf16)
    int s  = o0 >> 6;               // scale index (tile covers one scale)
    int lg = s + 1;                 // log2(window)
    int hh = 1 << lg;
    int Dd = 64 << (2 * lg);        // token dim
    int lgow = 7 - lg;
    unsigned short* obase = outp + ((size_t)s * 4 + b) * TOK;
    #pragma unroll
    for (int ii = 0; ii < 4; ii++) {
        int o = o0 + ty * 4 + ii;
        int ch = o & 63;
        float bia = bias[o];
        #pragma unroll
        for (int jj = 0; jj < 4; jj++) {
            int p = p0 + tx * 4 + jj;
            int yy = p >> 7, xx = p & 127;
            int oy = yy >> lg, wy = yy & (hh - 1);
            int ox = xx >> lg, wx = xx & (hh - 1);
            int tokn = (oy << lgow) + ox;
            int didx = (ch << (2 * lg)) + (wy << lg) + wx;
            obase[(size_t)tokn * Dd + didx] = f2bf(acc[ii][jj] + bia);
        }
    }
}

// ---------------------------------------------------------------------------
// S = scale * Q @ K^T   (bf16 token matrices [n][D], bf16 S out)
// grid: (N/64, N/64, nb); batch via blockIdx.z (stride TOK / N*N)
template<int N, int D>
__global__ __launch_bounds__(256) void s_kernel(
    const unsigned short* __restrict__ Qb, const unsigned short* __restrict__ Kb,
    unsigned short* __restrict__ S, float sc)
{
    int bz = blockIdx.z;
    const unsigned short* Q = Qb + (size_t)bz * TOK;
    const unsigned short* K = Kb + (size_t)bz * TOK;
    unsigned short* Sb = S + (size_t)bz * N * N;
    int i0 = blockIdx.x * 64, j0 = blockIdx.y * 64;

    __shared__ float As[16][64], Bs[16][64];   // [k][token]
    int t = threadIdx.x, tx = t & 15, ty = t >> 4, r = t >> 2, q = t & 3;

    float acc[4][4] = {};
    for (int kk = 0; kk < D; kk += 16) {
        float a4[4], b4[4];
        load4f(&Q[(size_t)(i0 + r) * D + kk + q * 4], a4);
        load4f(&K[(size_t)(j0 + r) * D + kk + q * 4], b4);
        __syncthreads();
        As[q*4+0][r] = a4[0]; As[q*4+1][r] = a4[1]; As[q*4+2][r] = a4[2]; As[q*4+3][r] = a4[3];
        Bs[q*4+0][r] = b4[0]; Bs[q*4+1][r] = b4[1]; Bs[q*4+2][r] = b4[2]; Bs[q*4+3][r] = b4[3];
        __syncthreads();
        #pragma unroll
        for (int k = 0; k < 16; k++) {
            float4 af = *(const float4*)&As[k][ty*4];
            float4 bf = *(const float4*)&Bs[k][tx*4];
            float ar[4] = {af.x, af.y, af.z, af.w};
            float br[4] = {bf.x, bf.y, bf.z, bf.w};
            #pragma unroll
            for (int ii = 0; ii < 4; ii++)
                #pragma unroll
                for (int jj = 0; jj < 4; jj++)
                    acc[ii][jj] = fmaf(ar[ii], br[jj], acc[ii][jj]);
        }
    }

    #pragma unroll
    for (int ii = 0; ii < 4; ii++) {
        int i = i0 + ty * 4 + ii;
        ushort4 st;
        st.x = f2bf(acc[ii][0] * sc);
        st.y = f2bf(acc[ii][1] * sc);
        st.z = f2bf(acc[ii][2] * sc);
        st.w = f2bf(acc[ii][3] * sc);
        *(ushort4*)&Sb[(size_t)i * N + j0 + tx * 4] = st;
    }
}

// scale-3 special: N=64, D=16384, K-split 16, fp32 atomic accumulation.
// grid: (1,1,64): z = b*16 + kc
__global__ __launch_bounds__(256) void s3_kernel(
    const unsigned short* __restrict__ Qb, const unsigned short* __restrict__ Kb,
    float* __restrict__ S, float sc)
{
    const int N = 64, D = 16384, KLEN = 1024;
    int b = blockIdx.z >> 4, kc = blockIdx.z & 15;
    const unsigned short* Q = Qb + (size_t)b * TOK;
    const unsigned short* K = Kb + (size_t)b * TOK;
    float* Sb = S + (size_t)b * N * N;
    int k0 = kc * KLEN;

    __shared__ float As[16][64], Bs[16][64];
    int t = threadIdx.x, tx = t & 15, ty = t >> 4, r = t >> 2, q = t & 3;

    float acc[4][4] = {};
    for (int kk = k0; kk < k0 + KLEN; kk += 16) {
        float a4[4], b4[4];
        load4f(&Q[(size_t)r * D + kk + q * 4], a4);
        load4f(&K[(size_t)r * D + kk + q * 4], b4);
        __syncthreads();
        As[q*4+0][r] = a4[0]; As[q*4+1][r] = a4[1]; As[q*4+2][r] = a4[2]; As[q*4+3][r] = a4[3];
        Bs[q*4+0][r] = b4[0]; Bs[q*4+1][r] = b4[1]; Bs[q*4+2][r] = b4[2]; Bs[q*4+3][r] = b4[3];
        __syncthreads();
        #pragma unroll
        for (int k = 0; k < 16; k++) {
            float4 af = *(const float4*)&As[k][ty*4];
            float4 bf = *(const float4*)&Bs[k][tx*4];
            float ar[4] = {af.x, af.y, af.z, af.w};
            float br[4] = {bf.x, bf.y, bf.z, bf.w};
            #pragma unroll
            for (int ii = 0; ii < 4; ii++)
                #pragma unroll
                for (int jj = 0; jj < 4; jj++)
                    acc[ii][jj] = fmaf(ar[ii], br[jj], acc[ii][jj]);
        }
    }

    #pragma unroll
    for (int ii = 0; ii < 4; ii++)
        #pragma unroll
        for (int jj = 0; jj < 4; jj++)
            atomicAdd(&Sb[(size_t)(ty * 4 + ii) * N + tx * 4 + jj], acc[ii][jj] * sc);
}

// ---------------------------------------------------------------------------
// in-place row softmax (T = unsigned short bf16 or float). grid: (n, nb)
template<typename T>
__global__ __launch_bounds__(256) void softmax_kernel(T* __restrict__ S, int n)
{
    int b = blockIdx.y;
    int row = blockIdx.x;
    T* rp = S + (size_t)b * n * n + (size_t)row * n;
    __shared__ float red[256];
    int t = threadIdx.x;

    float m = -1e30f;
    for (int j = t; j < n; j += 256) m = fmaxf(m, ld1(&rp[j]));
    red[t] = m; __syncthreads();
    for (int s = 128; s > 0; s >>= 1) { if (t < s) red[t] = fmaxf(red[t], red[t + s]); __syncthreads(); }
    m = red[0]; __syncthreads();

    float sum = 0.f;
    for (int j = t; j < n; j += 256) { float e = __expf(ld1(&rp[j]) - m); st1(&rp[j], e); sum += e; }
    red[t] = sum; __syncthreads();
    for (int s = 128; s > 0; s >>= 1) { if (t < s) red[t] += red[t + s]; __syncthreads(); }
    float inv = 1.f / red[0];
    for (int j = t; j < n; j += 256) st1(&rp[j], ld1(&rp[j]) * inv);
}

// ---------------------------------------------------------------------------
// O = P @ V, scattered back (bf16) to NCHW attention-output buffer.
// grid: (N/64, D/64, nb); batch for addressing = b0 + blockIdx.z
template<int N, int D, int HHW, int CH0, typename PT>
__global__ __launch_bounds__(256) void o_kernel(
    const PT* __restrict__ P, const unsigned short* __restrict__ Vb,
    unsigned short* __restrict__ ao, int b0)
{
    int bz = blockIdx.z;
    int b = b0 + bz;
    const PT* Pb = P + (size_t)bz * N * N;
    const unsigned short* V = Vb + (size_t)bz * TOK;
    int i0 = blockIdx.x * 64, d0 = blockIdx.y * 64;

    __shared__ float Ps[16][64];   // [j][i]
    __shared__ float Vs[16][64];   // [j][d]
    int t = threadIdx.x, tx = t & 15, ty = t >> 4, r = t >> 2, q = t & 3;
    int vr = t >> 4, vq = t & 15;

    float acc[4][4] = {};
    for (int j0 = 0; j0 < N; j0 += 16) {
        float p4[4], v4[4];
        load4f(&Pb[(size_t)(i0 + r) * N + j0 + q * 4], p4);
        load4f(&V[(size_t)(j0 + vr) * D + d0 + vq * 4], v4);
        __syncthreads();
        Ps[q*4+0][r] = p4[0]; Ps[q*4+1][r] = p4[1]; Ps[q*4+2][r] = p4[2]; Ps[q*4+3][r] = p4[3];
        Vs[vr][vq*4+0] = v4[0]; Vs[vr][vq*4+1] = v4[1]; Vs[vr][vq*4+2] = v4[2]; Vs[vr][vq*4+3] = v4[3];
        __syncthreads();
        #pragma unroll
        for (int k = 0; k < 16; k++) {
            float4 pf = *(const float4*)&Ps[k][ty*4];
            float4 vf = *(const float4*)&Vs[k][tx*4];
            float pr[4] = {pf.x, pf.y, pf.z, pf.w};
            float vrr[4] = {vf.x, vf.y, vf.z, vf.w};
            #pragma unroll
            for (int ii = 0; ii < 4; ii++)
                #pragma unroll
                for (int jj = 0; jj < 4; jj++)
                    acc[ii][jj] = fmaf(pr[ii], vrr[jj], acc[ii][jj]);
        }
    }

    constexpr int LG = (HHW == 2) ? 1 : (HHW == 4) ? 2 : (HHW == 8) ? 3 : 4;
    #pragma unroll
    for (int ii = 0; ii < 4; ii++) {
        int tokn = i0 + ty * 4 + ii;
        int oy = tokn >> (7 - LG), ox = tokn & ((1 << (7 - LG)) - 1);
        #pragma unroll
        for (int jj = 0; jj < 4; jj++) {
            int d = d0 + tx * 4 + jj;
            int ch = d >> (2 * LG);
            int rr = d & ((1 << (2 * LG)) - 1);
            int wy = rr >> LG, wx = rr & (HHW - 1);
            int yy = (oy << LG) + wy, xx = (ox << LG) + wx;
            ao[(((size_t)b * CC + CH0 + ch) * HH_ + yy) * WW_ + xx] = f2bf(acc[ii][jj]);
        }
    }
}

// ---------------------------------------------------------------------------
// 3x3 conv (SAME), tap-major K-loop GEMM, bf16 input, fp32 out.
// grid: (HWP/64, CC/64, BN)
__global__ __launch_bounds__(256) void conv3_kernel(
    const unsigned short* __restrict__ ao, const float* __restrict__ Wo,
    const float* __restrict__ bo, float* __restrict__ zout)
{
    int b = blockIdx.z;
    int yy = blockIdx.x >> 1, x0 = (blockIdx.x & 1) * 64;
    int o0 = blockIdx.y * 64;

    __shared__ float Ws[16][64];   // [k][o]
    __shared__ float Xs[16][64];   // [k][x]
    int t = threadIdx.x, tx = t & 15, ty = t >> 4, r = t >> 2, q = t & 3;

    float acc[4][4] = {};
    for (int kk = 0; kk < 2304; kk += 16) {
        int tap = kk >> 8;
        int dy = tap / 3 - 1, dx = tap % 3 - 1;
        int c0 = kk & 255;

        float wreg[4];
        #pragma unroll
        for (int e = 0; e < 4; e++)
            wreg[e] = Wo[(size_t)(o0 + r) * 2304 + (c0 + q * 4 + e) * 9 + tap];

        float xreg[4];
        int ys = yy + dy;
        #pragma unroll
        for (int e = 0; e < 4; e++) {
            int cr = (t >> 6) + e * 4;
            int xs = x0 + dx + (t & 63);
            float v = 0.f;
            if (ys >= 0 && ys < HH_ && xs >= 0 && xs < WW_)
                v = bf2f(ao[(((size_t)b * CC + c0 + cr) * HH_ + ys) * WW_ + xs]);
            xreg[e] = v;
        }
        __syncthreads();
        #pragma unroll
        for (int e = 0; e < 4; e++) {
            Ws[q * 4 + e][r] = wreg[e];
            Xs[(t >> 6) + e * 4][t & 63] = xreg[e];
        }
        __syncthreads();
        #pragma unroll
        for (int k = 0; k < 16; k++) {
            float4 wf = *(const float4*)&Ws[k][ty*4];
            float4 xf = *(const float4*)&Xs[k][tx*4];
            float wr[4] = {wf.x, wf.y, wf.z, wf.w};
            float xr2[4] = {xf.x, xf.y, xf.z, xf.w};
            #pragma unroll
            for (int ii = 0; ii < 4; ii++)
                #pragma unroll
                for (int jj = 0; jj < 4; jj++)
                    acc[ii][jj] = fmaf(wr[ii], xr2[jj], acc[ii][jj]);
        }
    }

    #pragma unroll
    for (int ii = 0; ii < 4; ii++) {
        int o = o0 + ty * 4 + ii;
        float bia = bo[o];
        float4 st = make_float4(acc[ii][0] + bia, acc[ii][1] + bia,
                                acc[ii][2] + bia, acc[ii][3] + bia);
        *(float4*)&zout[(((size_t)b * CC + o) * HH_ + yy) * WW_ + x0 + tx * 4] = st;
    }
}

// ---------------------------------------------------------------------------
// batch-norm stats: one block per channel, deterministic tree reduction
__global__ __launch_bounds__(256) void bn_stats_kernel(
    const float* __restrict__ z, const float* __restrict__ gamma,
    const float* __restrict__ beta, float* __restrict__ stats)
{
    int c = blockIdx.x;
    int t = threadIdx.x;
    float s = 0.f, s2 = 0.f;
    for (int i = t; i < BN * HWP; i += 256) {
        int b = i >> 14, p = i & (HWP - 1);
        float v = z[(((size_t)b * CC + c) << 14) + p];
        s += v; s2 = fmaf(v, v, s2);
    }
    __shared__ float r1[256], r2[256];
    r1[t] = s; r2[t] = s2; __syncthreads();
    for (int st = 128; st > 0; st >>= 1) {
        if (t < st) { r1[t] += r1[t + st]; r2[t] += r2[t + st]; }
        __syncthreads();
    }
    if (t == 0) {
        float inv_n = 1.f / (BN * HWP);
        float mean = r1[0] * inv_n;
        float var = r2[0] * inv_n - mean * mean;
        float rstd = rsqrtf(var + 1e-5f);
        float gs = gamma[c] * rstd;
        stats[c] = gs;
        stats[CC + c] = beta[c] - mean * gs;
    }
}

// bn scale/shift + LeakyReLU(0.2), in place on d_out. grid: 16384 blocks
__global__ __launch_bounds__(256) void bn_apply_kernel(
    float* __restrict__ z, const float* __restrict__ stats)
{
    size_t i4 = (size_t)blockIdx.x * 256 + threadIdx.x;
    size_t idx = i4 * 4;
    int c = (int)((idx >> 14) & 255);
    float gs = stats[c], gb = stats[CC + c];
    float4 v = *(float4*)&z[idx];
    v.x = fmaf(v.x, gs, gb); v.y = fmaf(v.y, gs, gb);
    v.z = fmaf(v.z, gs, gb); v.w = fmaf(v.w, gs, gb);
    v.x = v.x >= 0.f ? v.x : 0.2f * v.x;
    v.y = v.y >= 0.f ? v.y : 0.2f * v.y;
    v.z = v.z >= 0.f ? v.z : 0.2f * v.z;
    v.w = v.w >= 0.f ? v.w : 0.2f * v.w;
    *(float4*)&z[idx] = v;
}

// ---------------------------------------------------------------------------
extern "C" void kernel_launch(void* const* d_in, const int* in_sizes, int n_in,
                              void* d_out, int out_size, void* d_ws, size_t ws_size,
                              hipStream_t stream)
{
    const float* x     = (const float*)d_in[0];
    const float* y     = (const float*)d_in[1];
    const float* Wq    = (const float*)d_in[2];
    const float* bq    = (const float*)d_in[3];
    const float* Wk    = (const float*)d_in[4];
    const float* bk    = (const float*)d_in[5];
    const float* Wv    = (const float*)d_in[6];
    const float* bv    = (const float*)d_in[7];
    const float* Wo    = (const float*)d_in[8];
    const float* bo    = (const float*)d_in[9];
    const float* gamma = (const float*)d_in[10];
    const float* beta  = (const float*)d_in[11];
    float* out = (float*)d_out;

    unsigned short* qt  = (unsigned short*)d_ws;
    unsigned short* kt  = qt + (size_t)16777216;
    unsigned short* vt  = kt + (size_t)16777216;
    unsigned short* ao  = vt + (size_t)16777216;
    unsigned short* Sbf = ao + (size_t)16777216;
    float* stats = (float*)(Sbf + (size_t)16777216);
    float* S3    = stats + 512;

    dim3 blk(256);

    // zero scale-3 atomic accumulator (16384 floats)
    zero_kernel<<<dim3(64), blk, 0, stream>>>(S3);

    // q/k/v projections directly into bf16 token layout
    proj_kernel<<<dim3(HWP / 64, CC / 64, 12), blk, 0, stream>>>(
        x, y, Wq, bq, Wk, bk, Wv, bv, qt, kt, vt);

    // scale 0: n=4096, D=256, window 2 — per-batch (Sbf reused, 33.5 MB)
    for (int b = 0; b < 4; b++) {
        s_kernel<4096, 256><<<dim3(64, 64, 1), blk, 0, stream>>>(
            qt + (size_t)b * TOK, kt + (size_t)b * TOK, Sbf, 1.f / 16.f);
        softmax_kernel<unsigned short><<<dim3(4096, 1), blk, 0, stream>>>(Sbf, 4096);
        o_kernel<4096, 256, 2, 0, unsigned short><<<dim3(64, 4, 1), blk, 0, stream>>>(
            Sbf, vt + (size_t)b * TOK, ao, b);
    }
    // scale 1: n=1024, D=1024, window 4 (batched; 4*1024^2 bf16 = 8.4 MB)
    s_kernel<1024, 1024><<<dim3(16, 16, 4), blk, 0, stream>>>(
        qt + (size_t)4 * TOK, kt + (size_t)4 * TOK, Sbf, 1.f / 32.f);
    softmax_kernel<unsigned short><<<dim3(1024, 4), blk, 0, stream>>>(Sbf, 1024);
    o_kernel<1024, 1024, 4, 64, unsigned short><<<dim3(16, 16, 4), blk, 0, stream>>>(
        Sbf, vt + (size_t)4 * TOK, ao, 0);
    // scale 2: n=256, D=4096, window 8
    s_kernel<256, 4096><<<dim3(4, 4, 4), blk, 0, stream>>>(
        qt + (size_t)8 * TOK, kt + (size_t)8 * TOK, Sbf, 1.f / 64.f);
    softmax_kernel<unsigned short><<<dim3(256, 4), blk, 0, stream>>>(Sbf, 256);
    o_kernel<256, 4096, 8, 128, unsigned short><<<dim3(4, 64, 4), blk, 0, stream>>>(
        Sbf, vt + (size_t)8 * TOK, ao, 0);
    // scale 3: n=64, D=16384, window 16 — K-split 16, fp32 atomic S3
    s3_kernel<<<dim3(1, 1, 64), blk, 0, stream>>>(
        qt + (size_t)12 * TOK, kt + (size_t)12 * TOK, S3, 1.f / 128.f);
    softmax_kernel<float><<<dim3(64, 4), blk, 0, stream>>>(S3, 64);
    o_kernel<64, 16384, 16, 192, float><<<dim3(1, 256, 4), blk, 0, stream>>>(
        S3, vt + (size_t)12 * TOK, ao, 0);

    // conv3x3 -> d_out, then batchnorm + leaky relu in place
    conv3_kernel<<<dim3(HWP / 64, CC / 64, BN), blk, 0, stream>>>(ao, Wo, bo, out);
    bn_stats_kernel<<<dim3(CC), blk, 0, stream>>>(out, gamma, beta, stats);
    bn_apply_kernel<<<dim3(16384), blk, 0, stream>>>(out, stats);
}

// Round 3
// 1236.390 us; speedup vs baseline: 3.2426x; 3.2426x over previous
//
#include <hip/hip_runtime.h>
#include <math.h>

// Problem constants
#define BN 4
#define CC 256
#define HH_ 128
#define WW_ 128
#define HWP (HH_*WW_)           // 16384 pixels
#define TOK (64*HWP)            // 1,048,576 elems per (scale,batch) token matrix

// Workspace (bytes), total ~169.1 MB:
//  qt : bf16 [4 scale][4 b][tok][d]  33,554,432   (token-major, all scales)
//  kt : bf16 same                    33,554,432
//  vt : bf16 scales0-2 [d][tok], scale3 [tok][d]  33,554,432
//  aot: bf16 NHWC [b][y][x][c]       33,554,432   (attention out, conv input)
//  Sbf: bf16 score buffer (reused)   33,554,432   (scale0 per-batch 4096^2)
//  wpack: bf16 [256][9][256]          1,179,648
//  stats: 512 fp32                        2,048
//  S3 : fp32 [4][64][64]                 65,536
// Aliases: xt = Sbf (dead after proj), yt = aot (dead after proj).

typedef __attribute__((ext_vector_type(8))) short bf16x8;
typedef __attribute__((ext_vector_type(4))) float f32x4;

__device__ __forceinline__ float bf2f(unsigned short u) {
    return __uint_as_float(((unsigned)u) << 16);
}
__device__ __forceinline__ unsigned short f2bf(float f) {
    unsigned u = __float_as_uint(f);
    u += 0x7FFF + ((u >> 16) & 1);
    return (unsigned short)(u >> 16);
}
__device__ __forceinline__ void load4f(const unsigned short* p, float o[4]) {
    ushort4 v = *(const ushort4*)p;
    o[0] = bf2f(v.x); o[1] = bf2f(v.y); o[2] = bf2f(v.z); o[3] = bf2f(v.w);
}
__device__ __forceinline__ float ld1(const unsigned short* p) { return bf2f(*p); }
__device__ __forceinline__ float ld1(const float* p) { return *p; }
__device__ __forceinline__ void st1(unsigned short* p, float v) { *p = f2bf(v); }
__device__ __forceinline__ void st1(float* p, float v) { *p = v; }

// ===========================================================================
// Shared MFMA tile machinery: block = 256 thr = 4 waves; tile M=128,N=128,BK=64
// LDS: As/Bs [128][72] bf16 (pad 8). Wave w covers 64x64 quadrant (wm,wn).
// ===========================================================================
#define LDS_STRIDE 72

struct Tile32 { uint4 v[4]; };   // 32 bf16 per thread per operand per BK-iter

__device__ __forceinline__ Tile32 load_tile_bf16(
    const unsigned short* src, size_t stride, int t)
{
    int r = t >> 1, kc = (t & 1) * 32;
    const uint4* sp = (const uint4*)(src + (size_t)r * stride + kc);
    Tile32 o;
    o.v[0] = sp[0]; o.v[1] = sp[1]; o.v[2] = sp[2]; o.v[3] = sp[3];
    return o;
}

__device__ __forceinline__ Tile32 load_tile_f32(
    const float* src, size_t stride, int t)
{
    int r = t >> 1, kc = (t & 1) * 32;
    const float4* sp = (const float4*)(src + (size_t)r * stride + kc);
    unsigned short tmp[32];
    #pragma unroll
    for (int i = 0; i < 8; i++) {
        float4 v = sp[i];
        tmp[i*4+0] = f2bf(v.x); tmp[i*4+1] = f2bf(v.y);
        tmp[i*4+2] = f2bf(v.z); tmp[i*4+3] = f2bf(v.w);
    }
    Tile32 o;
    const uint4* tp = (const uint4*)tmp;
    o.v[0] = tp[0]; o.v[1] = tp[1]; o.v[2] = tp[2]; o.v[3] = tp[3];
    return o;
}

__device__ __forceinline__ void store_tile(
    unsigned short* lds, const Tile32& d, int t)
{
    int r = t >> 1, kc = (t & 1) * 32;
    uint4* dp = (uint4*)&lds[r * LDS_STRIDE + kc];
    dp[0] = d.v[0]; dp[1] = d.v[1]; dp[2] = d.v[2]; dp[3] = d.v[3];
}

__device__ __forceinline__ void mfma_iter(
    const unsigned short* As, const unsigned short* Bs,
    int wm, int wn, int lr, int quad, f32x4 acc[4][4])
{
    #pragma unroll
    for (int s = 0; s < 2; s++) {
        bf16x8 af[4], bfr[4];
        #pragma unroll
        for (int i = 0; i < 4; i++)
            af[i] = *(const bf16x8*)&As[(wm*64 + i*16 + lr) * LDS_STRIDE + s*32 + quad*8];
        #pragma unroll
        for (int j = 0; j < 4; j++)
            bfr[j] = *(const bf16x8*)&Bs[(wn*64 + j*16 + lr) * LDS_STRIDE + s*32 + quad*8];
        #pragma unroll
        for (int i = 0; i < 4; i++)
            #pragma unroll
            for (int j = 0; j < 4; j++)
                acc[i][j] = __builtin_amdgcn_mfma_f32_16x16x32_bf16(
                    af[i], bfr[j], acc[i][j], 0, 0, 0);
    }
}

// ---------------------------------------------------------------------------
__global__ __launch_bounds__(256) void zero_kernel(float* __restrict__ p)
{
    p[blockIdx.x * 256 + threadIdx.x] = 0.f;
}

// ---------------------------------------------------------------------------
// NCHW fp32 -> NHWC bf16 for x and y. grid (256 p-tiles, 4 c-tiles, 8)
__global__ __launch_bounds__(256) void nchw_to_nhwc(
    const float* __restrict__ x, const float* __restrict__ y,
    unsigned short* __restrict__ xt, unsigned short* __restrict__ yt)
{
    __shared__ unsigned short T[64 * 72];
    int z = blockIdx.z;
    int b = z & 3, which = z >> 2;
    const float* src = (which ? y : x) + (size_t)b * CC * HWP;
    unsigned short* dst = (which ? yt : xt) + (size_t)b * HWP * CC;
    int p0 = blockIdx.x * 64, c0 = blockIdx.y * 64;
    int t = threadIdx.x;

    int cl = t >> 2, pc = (t & 3) * 16;
    #pragma unroll
    for (int e = 0; e < 16; e += 4) {
        float4 v = *(const float4*)&src[(size_t)(c0 + cl) * HWP + p0 + pc + e];
        T[(pc + e + 0) * 72 + cl] = f2bf(v.x);
        T[(pc + e + 1) * 72 + cl] = f2bf(v.y);
        T[(pc + e + 2) * 72 + cl] = f2bf(v.z);
        T[(pc + e + 3) * 72 + cl] = f2bf(v.w);
    }
    __syncthreads();
    int p = t >> 2, cc = (t & 3) * 16;
    uint4 a = *(uint4*)&T[p * 72 + cc];
    uint4 bsec = *(uint4*)&T[p * 72 + cc + 8];
    uint4* dp = (uint4*)&dst[(size_t)(p0 + p) * CC + c0 + cc];
    dp[0] = a; dp[1] = bsec;
}

// ---------------------------------------------------------------------------
// pack conv weights: Wo [o][c][3][3] fp32 -> wpack [o][tap][c] bf16
__global__ __launch_bounds__(256) void wpack_kernel(
    const float* __restrict__ Wo, unsigned short* __restrict__ wpack)
{
    int o = blockIdx.x, c = threadIdx.x;
    const float* wr = Wo + ((size_t)o * CC + c) * 9;
    #pragma unroll
    for (int tap = 0; tap < 9; tap++)
        wpack[((size_t)o * 9 + tap) * CC + c] = f2bf(wr[tap]);
}

// ---------------------------------------------------------------------------
// proj: C[o][p] = W[o][c] * X[p][c]^T + bias, scattered to token layouts.
// grid: (128 p-tiles, 2 o-tiles, 12) z = which*4 + b
__global__ __launch_bounds__(256) void proj_gemm(
    const unsigned short* __restrict__ xt, const unsigned short* __restrict__ yt,
    const float* __restrict__ Wq, const float* __restrict__ bq,
    const float* __restrict__ Wk, const float* __restrict__ bk,
    const float* __restrict__ Wv, const float* __restrict__ bv,
    unsigned short* __restrict__ qt, unsigned short* __restrict__ kt,
    unsigned short* __restrict__ vt)
{
    __shared__ unsigned short As[128 * LDS_STRIDE], Bs[128 * LDS_STRIDE];
    int z = blockIdx.z, b = z & 3, which = z >> 2;
    const unsigned short* src = (which == 0) ? xt : yt;
    const float* Wm   = (which == 0) ? Wq : (which == 1 ? Wk : Wv);
    const float* bias = (which == 0) ? bq : (which == 1 ? bk : bv);
    unsigned short* outp = (which == 0) ? qt : (which == 1 ? kt : vt);

    int m0 = blockIdx.y * 128;   // output channels
    int n0 = blockIdx.x * 128;   // pixels
    const float* A = Wm + (size_t)m0 * CC;
    const unsigned short* B = src + ((size_t)b * HWP + n0) * CC;

    int t = threadIdx.x, w = t >> 6, lane = t & 63;
    int quad = lane >> 4, lr = lane & 15, wm = w >> 1, wn = w & 1;

    f32x4 acc[4][4];
    #pragma unroll
    for (int i = 0; i < 4; i++)
        #pragma unroll
        for (int j = 0; j < 4; j++) acc[i][j] = (f32x4){0.f, 0.f, 0.f, 0.f};

    for (int k0 = 0; k0 < CC; k0 += 64) {
        Tile32 ta = load_tile_f32(A + k0, CC, t);
        Tile32 tb = load_tile_bf16(B + k0, CC, t);
        __syncthreads();
        store_tile(As, ta, t); store_tile(Bs, tb, t);
        __syncthreads();
        mfma_iter(As, Bs, wm, wn, lr, quad, acc);
    }

    #pragma unroll
    for (int i = 0; i < 4; i++) {
        int obase = m0 + wm * 64 + i * 16 + quad * 4;
        #pragma unroll
        for (int rr = 0; rr < 4; rr++) {
            int o = obase + rr;
            int s = o >> 6, lg = s + 1;
            int ch = o & 63;
            float bia = bias[o];
            unsigned short* ob = outp + ((size_t)s * 4 + b) * TOK;
            #pragma unroll
            for (int j = 0; j < 4; j++) {
                int p = n0 + wn * 64 + j * 16 + lr;
                int yy = p >> 7, xx = p & 127;
                int oy = yy >> lg, wy = yy & ((1 << lg) - 1);
                int ox = xx >> lg, wx = xx & ((1 << lg) - 1);
                int tokn = (oy << (7 - lg)) + ox;
                int didx = (ch << (2 * lg)) + (wy << lg) + wx;
                size_t idx;
                if (which == 2 && s < 3)
                    idx = ((size_t)didx << (14 - 2 * lg)) + tokn;   // [d][tok]
                else
                    idx = ((size_t)tokn << (6 + 2 * lg)) + didx;    // [tok][d]
                ob[idx] = f2bf(acc[i][j][rr] + bia);
            }
        }
    }
}

// ---------------------------------------------------------------------------
// S = sc * Q K^T. Q,K bf16 [tok][d]. grid: (N/128, N/128, nb)
template<int NTOK, int DD>
__global__ __launch_bounds__(256) void s_gemm(
    const unsigned short* __restrict__ Qb, const unsigned short* __restrict__ Kb,
    unsigned short* __restrict__ Sb, float sc)
{
    __shared__ unsigned short As[128 * LDS_STRIDE], Bs[128 * LDS_STRIDE];
    int bz = blockIdx.z;
    int m0 = blockIdx.y * 128, n0 = blockIdx.x * 128;
    const unsigned short* Q = Qb + (size_t)bz * TOK + (size_t)m0 * DD;
    const unsigned short* K = Kb + (size_t)bz * TOK + (size_t)n0 * DD;
    unsigned short* S = Sb + (size_t)bz * NTOK * NTOK;

    int t = threadIdx.x, w = t >> 6, lane = t & 63;
    int quad = lane >> 4, lr = lane & 15, wm = w >> 1, wn = w & 1;

    f32x4 acc[4][4];
    #pragma unroll
    for (int i = 0; i < 4; i++)
        #pragma unroll
        for (int j = 0; j < 4; j++) acc[i][j] = (f32x4){0.f, 0.f, 0.f, 0.f};

    for (int k0 = 0; k0 < DD; k0 += 64) {
        Tile32 ta = load_tile_bf16(Q + k0, DD, t);
        Tile32 tb = load_tile_bf16(K + k0, DD, t);
        __syncthreads();
        store_tile(As, ta, t); store_tile(Bs, tb, t);
        __syncthreads();
        mfma_iter(As, Bs, wm, wn, lr, quad, acc);
    }

    #pragma unroll
    for (int i = 0; i < 4; i++) {
        int m = m0 + wm * 64 + i * 16 + quad * 4;
        #pragma unroll
        for (int j = 0; j < 4; j++) {
            int n = n0 + wn * 64 + j * 16 + lr;
            #pragma unroll
            for (int rr = 0; rr < 4; rr++)
                S[(size_t)(m + rr) * NTOK + n] = f2bf(acc[i][j][rr] * sc);
        }
    }
}

// ---------------------------------------------------------------------------
// O = P V with V stored [d][tok]; epilogue scatters NHWC bf16.
// grid: (DD/128, NTOK/128, nb)
template<int NTOK, int DD, int LG, int CH0>
__global__ __launch_bounds__(256) void o_gemm(
    const unsigned short* __restrict__ Pb, const unsigned short* __restrict__ Vb,
    unsigned short* __restrict__ aot, int b0)
{
    __shared__ unsigned short As[128 * LDS_STRIDE], Bs[128 * LDS_STRIDE];
    int bz = blockIdx.z, b = b0 + bz;
    int m0 = blockIdx.y * 128, n0 = blockIdx.x * 128;
    const unsigned short* P = Pb + (size_t)bz * NTOK * NTOK + (size_t)m0 * NTOK;
    const unsigned short* V = Vb + (size_t)bz * TOK + (size_t)n0 * NTOK;

    int t = threadIdx.x, w = t >> 6, lane = t & 63;
    int quad = lane >> 4, lr = lane & 15, wm = w >> 1, wn = w & 1;

    f32x4 acc[4][4];
    #pragma unroll
    for (int i = 0; i < 4; i++)
        #pragma unroll
        for (int j = 0; j < 4; j++) acc[i][j] = (f32x4){0.f, 0.f, 0.f, 0.f};

    for (int k0 = 0; k0 < NTOK; k0 += 64) {
        Tile32 ta = load_tile_bf16(P + k0, NTOK, t);
        Tile32 tb = load_tile_bf16(V + k0, NTOK, t);
        __syncthreads();
        store_tile(As, ta, t); store_tile(Bs, tb, t);
        __syncthreads();
        mfma_iter(As, Bs, wm, wn, lr, quad, acc);
    }

    #pragma unroll
    for (int i = 0; i < 4; i++) {
        int tb0 = m0 + wm * 64 + i * 16 + quad * 4;
        #pragma unroll
        for (int rr = 0; rr < 4; rr++) {
            int tokn = tb0 + rr;
            int oy = tokn >> (7 - LG), ox = tokn & ((1 << (7 - LG)) - 1);
            #pragma unroll
            for (int j = 0; j < 4; j++) {
                int d = n0 + wn * 64 + j * 16 + lr;
                int ch = d >> (2 * LG);
                int r2 = d & ((1 << (2 * LG)) - 1);
                int wy = r2 >> LG, wx = r2 & ((1 << LG) - 1);
                int yy = (oy << LG) + wy, xx = (ox << LG) + wx;
                aot[((size_t)b * HWP + yy * WW_ + xx) * CC + CH0 + ch] =
                    f2bf(acc[i][j][rr]);
            }
        }
    }
}

// ---------------------------------------------------------------------------
// conv3x3: out[o][p] = sum_{tap,c} wpack[o][tap][c] * aot[p+shift][c] + bo
// grid: (128 y-rows, 2 o-tiles, 4 b)
__device__ __forceinline__ Tile32 load_tile_conv(
    const unsigned short* aob, int ys, int dx, int cbase, int t)
{
    int r = t >> 1, kc = (t & 1) * 32;
    int xs = r + dx;
    Tile32 o;
    if (ys >= 0 && ys < HH_ && xs >= 0 && xs < WW_) {
        const uint4* sp = (const uint4*)(aob + ((size_t)ys * WW_ + xs) * CC + cbase + kc);
        o.v[0] = sp[0]; o.v[1] = sp[1]; o.v[2] = sp[2]; o.v[3] = sp[3];
    } else {
        uint4 zz = make_uint4(0, 0, 0, 0);
        o.v[0] = zz; o.v[1] = zz; o.v[2] = zz; o.v[3] = zz;
    }
    return o;
}

__global__ __launch_bounds__(256) void conv_gemm(
    const unsigned short* __restrict__ aot, const unsigned short* __restrict__ wpack,
    const float* __restrict__ bo, float* __restrict__ zout)
{
    __shared__ unsigned short As[128 * LDS_STRIDE], Bs[128 * LDS_STRIDE];
    int yrow = blockIdx.x;
    int o0 = blockIdx.y * 128;
    int b = blockIdx.z;
    const unsigned short* aob = aot + (size_t)b * HWP * CC;
    const unsigned short* wsrc = wpack + (size_t)o0 * 2304;

    int t = threadIdx.x, w = t >> 6, lane = t & 63;
    int quad = lane >> 4, lr = lane & 15, wm = w >> 1, wn = w & 1;

    f32x4 acc[4][4];
    #pragma unroll
    for (int i = 0; i < 4; i++)
        #pragma unroll
        for (int j = 0; j < 4; j++) acc[i][j] = (f32x4){0.f, 0.f, 0.f, 0.f};

    for (int tap = 0; tap < 9; tap++) {
        int dy = tap / 3 - 1, dx = tap % 3 - 1;
        int ys = yrow + dy;
        for (int cb = 0; cb < CC; cb += 64) {
            Tile32 ta = load_tile_bf16(wsrc + tap * CC + cb, 2304, t);
            Tile32 tb = load_tile_conv(aob, ys, dx, cb, t);
            __syncthreads();
            store_tile(As, ta, t); store_tile(Bs, tb, t);
            __syncthreads();
            mfma_iter(As, Bs, wm, wn, lr, quad, acc);
        }
    }

    #pragma unroll
    for (int i = 0; i < 4; i++) {
        int ob = o0 + wm * 64 + i * 16 + quad * 4;
        #pragma unroll
        for (int j = 0; j < 4; j++) {
            int x = wn * 64 + j * 16 + lr;
            #pragma unroll
            for (int rr = 0; rr < 4; rr++) {
                int o = ob + rr;
                zout[((size_t)(b * CC + o)) * HWP + yrow * WW_ + x] =
                    acc[i][j][rr] + bo[o];
            }
        }
    }
}

// ---------------------------------------------------------------------------
// scale-3 S: N=64, D=16384, K-split 16, fp32 atomic acc. grid (1,1,64)
__global__ __launch_bounds__(256) void s3_kernel(
    const unsigned short* __restrict__ Qb, const unsigned short* __restrict__ Kb,
    float* __restrict__ S, float sc)
{
    const int N = 64, D = 16384, KLEN = 1024;
    int b = blockIdx.z >> 4, kc = blockIdx.z & 15;
    const unsigned short* Q = Qb + (size_t)b * TOK;
    const unsigned short* K = Kb + (size_t)b * TOK;
    float* Sb = S + (size_t)b * N * N;
    int k0 = kc * KLEN;

    __shared__ float As[16][64], Bs[16][64];
    int t = threadIdx.x, tx = t & 15, ty = t >> 4, r = t >> 2, q = t & 3;

    float acc[4][4] = {};
    for (int kk = k0; kk < k0 + KLEN; kk += 16) {
        float a4[4], b4[4];
        load4f(&Q[(size_t)r * D + kk + q * 4], a4);
        load4f(&K[(size_t)r * D + kk + q * 4], b4);
        __syncthreads();
        As[q*4+0][r] = a4[0]; As[q*4+1][r] = a4[1]; As[q*4+2][r] = a4[2]; As[q*4+3][r] = a4[3];
        Bs[q*4+0][r] = b4[0]; Bs[q*4+1][r] = b4[1]; Bs[q*4+2][r] = b4[2]; Bs[q*4+3][r] = b4[3];
        __syncthreads();
        #pragma unroll
        for (int k = 0; k < 16; k++) {
            float4 af = *(const float4*)&As[k][ty*4];
            float4 bf = *(const float4*)&Bs[k][tx*4];
            float ar[4] = {af.x, af.y, af.z, af.w};
            float br[4] = {bf.x, bf.y, bf.z, bf.w};
            #pragma unroll
            for (int ii = 0; ii < 4; ii++)
                #pragma unroll
                for (int jj = 0; jj < 4; jj++)
                    acc[ii][jj] = fmaf(ar[ii], br[jj], acc[ii][jj]);
        }
    }

    #pragma unroll
    for (int ii = 0; ii < 4; ii++)
        #pragma unroll
        for (int jj = 0; jj < 4; jj++)
            atomicAdd(&Sb[(size_t)(ty * 4 + ii) * N + tx * 4 + jj], acc[ii][jj] * sc);
}

// ---------------------------------------------------------------------------
// in-place row softmax. grid: (n, nb)
template<typename T>
__global__ __launch_bounds__(256) void softmax_kernel(T* __restrict__ S, int n)
{
    int b = blockIdx.y;
    int row = blockIdx.x;
    T* rp = S + (size_t)b * n * n + (size_t)row * n;
    __shared__ float red[256];
    int t = threadIdx.x;

    float m = -1e30f;
    for (int j = t; j < n; j += 256) m = fmaxf(m, ld1(&rp[j]));
    red[t] = m; __syncthreads();
    for (int s = 128; s > 0; s >>= 1) { if (t < s) red[t] = fmaxf(red[t], red[t + s]); __syncthreads(); }
    m = red[0]; __syncthreads();

    float sum = 0.f;
    for (int j = t; j < n; j += 256) { float e = __expf(ld1(&rp[j]) - m); st1(&rp[j], e); sum += e; }
    red[t] = sum; __syncthreads();
    for (int s = 128; s > 0; s >>= 1) { if (t < s) red[t] += red[t + s]; __syncthreads(); }
    float inv = 1.f / red[0];
    for (int j = t; j < n; j += 256) st1(&rp[j], ld1(&rp[j]) * inv);
}

// ---------------------------------------------------------------------------
// scale-3 O = P(fp32 64x64) V(bf16 [tok][d]); NHWC bf16 out. grid (1,256,4)
__global__ __launch_bounds__(256) void o3_kernel(
    const float* __restrict__ P, const unsigned short* __restrict__ Vb,
    unsigned short* __restrict__ aot)
{
    const int N = 64, D = 16384, LG = 4, CH0 = 192;
    int bz = blockIdx.z;
    const float* Pb = P + (size_t)bz * N * N;
    const unsigned short* V = Vb + (size_t)bz * TOK;
    int i0 = blockIdx.x * 64, d0 = blockIdx.y * 64;

    __shared__ float Ps[16][64];
    __shared__ float Vs[16][64];
    int t = threadIdx.x, tx = t & 15, ty = t >> 4, r = t >> 2, q = t & 3;
    int vr = t >> 4, vq = t & 15;

    float acc[4][4] = {};
    for (int j0 = 0; j0 < N; j0 += 16) {
        float p4[4], v4[4];
        float4 pv = *(const float4*)&Pb[(size_t)(i0 + r) * N + j0 + q * 4];
        p4[0] = pv.x; p4[1] = pv.y; p4[2] = pv.z; p4[3] = pv.w;
        load4f(&V[(size_t)(j0 + vr) * D + d0 + vq * 4], v4);
        __syncthreads();
        Ps[q*4+0][r] = p4[0]; Ps[q*4+1][r] = p4[1]; Ps[q*4+2][r] = p4[2]; Ps[q*4+3][r] = p4[3];
        Vs[vr][vq*4+0] = v4[0]; Vs[vr][vq*4+1] = v4[1]; Vs[vr][vq*4+2] = v4[2]; Vs[vr][vq*4+3] = v4[3];
        __syncthreads();
        #pragma unroll
        for (int k = 0; k < 16; k++) {
            float4 pf = *(const float4*)&Ps[k][ty*4];
            float4 vf = *(const float4*)&Vs[k][tx*4];
            float pr[4] = {pf.x, pf.y, pf.z, pf.w};
            float vrr[4] = {vf.x, vf.y, vf.z, vf.w};
            #pragma unroll
            for (int ii = 0; ii < 4; ii++)
                #pragma unroll
                for (int jj = 0; jj < 4; jj++)
                    acc[ii][jj] = fmaf(pr[ii], vrr[jj], acc[ii][jj]);
        }
    }

    #pragma unroll
    for (int ii = 0; ii < 4; ii++) {
        int tokn = i0 + ty * 4 + ii;
        int oy = tokn >> (7 - LG), ox = tokn & ((1 << (7 - LG)) - 1);
        #pragma unroll
        for (int jj = 0; jj < 4; jj++) {
            int d = d0 + tx * 4 + jj;
            int ch = d >> (2 * LG);
            int r2 = d & ((1 << (2 * LG)) - 1);
            int wy = r2 >> LG, wx = r2 & ((1 << LG) - 1);
            int yy = (oy << LG) + wy, xx = (ox << LG) + wx;
            aot[((size_t)bz * HWP + yy * WW_ + xx) * CC + CH0 + ch] = f2bf(acc[ii][jj]);
        }
    }
}

// ---------------------------------------------------------------------------
__global__ __launch_bounds__(256) void bn_stats_kernel(
    const float* __restrict__ z, const float* __restrict__ gamma,
    const float* __restrict__ beta, float* __restrict__ stats)
{
    int c = blockIdx.x;
    int t = threadIdx.x;
    float s = 0.f, s2 = 0.f;
    for (int i = t; i < BN * HWP; i += 256) {
        int b = i >> 14, p = i & (HWP - 1);
        float v = z[(((size_t)b * CC + c) << 14) + p];
        s += v; s2 = fmaf(v, v, s2);
    }
    __shared__ float r1[256], r2[256];
    r1[t] = s; r2[t] = s2; __syncthreads();
    for (int st = 128; st > 0; st >>= 1) {
        if (t < st) { r1[t] += r1[t + st]; r2[t] += r2[t + st]; }
        __syncthreads();
    }
    if (t == 0) {
        float inv_n = 1.f / (BN * HWP);
        float mean = r1[0] * inv_n;
        float var = r2[0] * inv_n - mean * mean;
        float rstd = rsqrtf(var + 1e-5f);
        float gs = gamma[c] * rstd;
        stats[c] = gs;
        stats[CC + c] = beta[c] - mean * gs;
    }
}

__global__ __launch_bounds__(256) void bn_apply_kernel(
    float* __restrict__ z, const float* __restrict__ stats)
{
    size_t i4 = (size_t)blockIdx.x * 256 + threadIdx.x;
    size_t idx = i4 * 4;
    int c = (int)((idx >> 14) & 255);
    float gs = stats[c], gb = stats[CC + c];
    float4 v = *(float4*)&z[idx];
    v.x = fmaf(v.x, gs, gb); v.y = fmaf(v.y, gs, gb);
    v.z = fmaf(v.z, gs, gb); v.w = fmaf(v.w, gs, gb);
    v.x = v.x >= 0.f ? v.x : 0.2f * v.x;
    v.y = v.y >= 0.f ? v.y : 0.2f * v.y;
    v.z = v.z >= 0.f ? v.z : 0.2f * v.z;
    v.w = v.w >= 0.f ? v.w : 0.2f * v.w;
    *(float4*)&z[idx] = v;
}

// ---------------------------------------------------------------------------
extern "C" void kernel_launch(void* const* d_in, const int* in_sizes, int n_in,
                              void* d_out, int out_size, void* d_ws, size_t ws_size,
                              hipStream_t stream)
{
    const float* x     = (const float*)d_in[0];
    const float* y     = (const float*)d_in[1];
    const float* Wq    = (const float*)d_in[2];
    const float* bq    = (const float*)d_in[3];
    const float* Wk    = (const float*)d_in[4];
    const float* bk    = (const float*)d_in[5];
    const float* Wv    = (const float*)d_in[6];
    const float* bv    = (const float*)d_in[7];
    const float* Wo    = (const float*)d_in[8];
    const float* bo    = (const float*)d_in[9];
    const float* gamma = (const float*)d_in[10];
    const float* beta  = (const float*)d_in[11];
    float* out = (float*)d_out;

    unsigned short* qt    = (unsigned short*)d_ws;
    unsigned short* kt    = qt + (size_t)16777216;
    unsigned short* vt    = kt + (size_t)16777216;
    unsigned short* aot   = vt + (size_t)16777216;
    unsigned short* Sbf   = aot + (size_t)16777216;
    unsigned short* wpack = Sbf + (size_t)16777216;
    float* stats = (float*)(wpack + (size_t)589824);
    float* S3    = stats + 512;
    // aliases (dead after proj_gemm):
    unsigned short* xt = Sbf;
    unsigned short* yt = aot;

    dim3 blk(256);

    zero_kernel<<<dim3(64), blk, 0, stream>>>(S3);
    nchw_to_nhwc<<<dim3(256, 4, 8), blk, 0, stream>>>(x, y, xt, yt);
    wpack_kernel<<<dim3(256), blk, 0, stream>>>(Wo, wpack);

    proj_gemm<<<dim3(128, 2, 12), blk, 0, stream>>>(
        xt, yt, Wq, bq, Wk, bk, Wv, bv, qt, kt, vt);

    // scale 0: n=4096, D=256, window 2 — per batch (Sbf reused)
    for (int b = 0; b < 4; b++) {
        s_gemm<4096, 256><<<dim3(32, 32, 1), blk, 0, stream>>>(
            qt + (size_t)b * TOK, kt + (size_t)b * TOK, Sbf, 1.f / 16.f);
        softmax_kernel<unsigned short><<<dim3(4096, 1), blk, 0, stream>>>(Sbf, 4096);
        o_gemm<4096, 256, 1, 0><<<dim3(2, 32, 1), blk, 0, stream>>>(
            Sbf, vt + (size_t)b * TOK, aot, b);
    }
    // scale 1: n=1024, D=1024, window 4
    s_gemm<1024, 1024><<<dim3(8, 8, 4), blk, 0, stream>>>(
        qt + (size_t)4 * TOK, kt + (size_t)4 * TOK, Sbf, 1.f / 32.f);
    softmax_kernel<unsigned short><<<dim3(1024, 4), blk, 0, stream>>>(Sbf, 1024);
    o_gemm<1024, 1024, 2, 64><<<dim3(8, 8, 4), blk, 0, stream>>>(
        Sbf, vt + (size_t)4 * TOK, aot, 0);
    // scale 2: n=256, D=4096, window 8
    s_gemm<256, 4096><<<dim3(2, 2, 4), blk, 0, stream>>>(
        qt + (size_t)8 * TOK, kt + (size_t)8 * TOK, Sbf, 1.f / 64.f);
    softmax_kernel<unsigned short><<<dim3(256, 4), blk, 0, stream>>>(Sbf, 256);
    o_gemm<256, 4096, 3, 128><<<dim3(32, 2, 4), blk, 0, stream>>>(
        Sbf, vt + (size_t)8 * TOK, aot, 0);
    // scale 3: n=64, D=16384, window 16 — fp32 K-split path
    s3_kernel<<<dim3(1, 1, 64), blk, 0, stream>>>(
        qt + (size_t)12 * TOK, kt + (size_t)12 * TOK, S3, 1.f / 128.f);
    softmax_kernel<float><<<dim3(64, 4), blk, 0, stream>>>(S3, 64);
    o3_kernel<<<dim3(1, 256, 4), blk, 0, stream>>>(S3, vt + (size_t)12 * TOK, aot);

    conv_gemm<<<dim3(128, 2, 4), blk, 0, stream>>>(aot, wpack, bo, out);
    bn_stats_kernel<<<dim3(CC), blk, 0, stream>>>(out, gamma, beta, stats);
    bn_apply_kernel<<<dim3(16384), blk, 0, stream>>>(out, stats);
}